// Round 14
// baseline (554.014 us; speedup 1.0000x reference)
//
#include <hip/hip_runtime.h>
#include <hip/hip_bf16.h>
#include <math.h>

#define Bdim 8
#define Tdim 1024
#define Cdim 768
#define Hdim 24
#define Ndim 32
#define BTdim (Bdim*Tdim)

typedef __attribute__((ext_vector_type(8))) short bf16x8;
typedef __attribute__((ext_vector_type(4))) float f32x4;
typedef __hip_bfloat16 bf16;

__device__ __forceinline__ float sigm(float x){ return 1.f/(1.f+expf(-x)); }
__device__ __forceinline__ float softplusf(float x){ return fmaxf(x,0.f) + log1pf(expf(-fabsf(x))); }
__device__ __forceinline__ float bf2f(bf16 v){ return __bfloat162float(v); }
__device__ __forceinline__ float us2f(unsigned short s){ return __builtin_bit_cast(float, (unsigned)s<<16); }

template<int CTRL>
__device__ __forceinline__ float dpp_add(float x){
  int xi = __builtin_bit_cast(int, x);
  int yi = __builtin_amdgcn_mov_dpp(xi, CTRL, 0xF, 0xF, true);
  return x + __builtin_bit_cast(float, yi);
}
__device__ __forceinline__ float red32(float x){
  x = dpp_add<0xB1>(x);
  x = dpp_add<0x4E>(x);
  x = dpp_add<0x141>(x);
  x = dpp_add<0x140>(x);
  x += __shfl_xor(x, 16);
  return x;
}
__device__ __forceinline__ float red16(float x){
  x = dpp_add<0xB1>(x);
  x = dpp_add<0x4E>(x);
  x = dpp_add<0x141>(x);
  x = dpp_add<0x140>(x);
  return x;
}

#define GLDS16(gp, lp) __builtin_amdgcn_global_load_lds((const __attribute__((address_space(1))) void*)(gp), (__attribute__((address_space(3))) void*)(lp), 16, 0, 0)

// ---------------- K1: token shift ----------------
__global__ void k1_shift(const float* __restrict__ x, const float* __restrict__ maa_x,
                         bf16* __restrict__ xxx) {
  int idx = blockIdx.x*256 + threadIdx.x;
  if (idx >= BTdim*Cdim) return;
  int c = idx % Cdim; int row = idx / Cdim; int t = row % Tdim;
  float xv = x[idx];
  float xp = (t==0) ? 0.f : x[idx - Cdim];
  xxx[idx] = __float2bfloat16(xv + (xp - xv)*maa_x[c]);
}

// ---------------- merged: big-weight transpose + small-weight pack ----------------
__global__ __launch_bounds__(256) void kcp(const float* __restrict__ W0, const float* __restrict__ W1,
    const float* __restrict__ W2, const float* __restrict__ W3,
    bf16* __restrict__ T0, bf16* __restrict__ T1, bf16* __restrict__ T2, bf16* __restrict__ T3,
    const float* __restrict__ dw1, const float* __restrict__ aaa_w1,
    const float* __restrict__ ma_w1, const float* __restrict__ kkk_w1, const float* __restrict__ mk_w1,
    const float* __restrict__ mv_w1, const float* __restrict__ gate_w1, const float* __restrict__ maa_w1,
    const float* __restrict__ dw2, const float* __restrict__ aaa_w2, const float* __restrict__ ma_w2,
    const float* __restrict__ kkk_w2, const float* __restrict__ mk_w2, const float* __restrict__ mv_w2,
    const float* __restrict__ gate_w2,
    bf16* __restrict__ PWwa, bf16* __restrict__ PWk, bf16* __restrict__ PWv,
    bf16* __restrict__ PWrg, bf16* __restrict__ PWmaa,
    bf16* __restrict__ W2wa, bf16* __restrict__ W2k, bf16* __restrict__ W2v, bf16* __restrict__ W2g){
  const int bid = blockIdx.x;
  if (bid < 2304) {
    __shared__ float tile[32][33];
    const int z = bid/576, rem = bid - z*576;
    const int by = (rem/24)*32, bx = (rem%24)*32;
    const float* Wsrc[4] = {W0,W1,W2,W3};
    bf16* Tdst[4] = {T0,T1,T2,T3};
    const float* W = Wsrc[z];
    bf16* T = Tdst[z];
    int tx = threadIdx.x & 31, ty = threadIdx.x >> 5;
    #pragma unroll
    for (int q=0;q<32;q+=8) tile[ty+q][tx] = W[(size_t)(by+ty+q)*Cdim + bx+tx];
    __syncthreads();
    #pragma unroll
    for (int q=0;q<32;q+=8) T[(size_t)(bx+ty+q)*Cdim + by+tx] = __float2bfloat16(tile[tx][ty+q]);
    return;
  }
  int idx = (bid-2304)*256 + threadIdx.x;
  if (idx < 491520) {
    int buf = idx / 98304, rem = idx - buf*98304;
    int n = rem / 768, kk = rem - n*768;
    float val = 0.f;
    bf16* dst;
    switch(buf){
      case 0: dst=PWwa; if(n<64) val=dw1[(size_t)kk*64+n]; else if(n<88) val=aaa_w1[(size_t)kk*24+(n-64)]; else if(n<112) val=ma_w1[(size_t)kk*24+(n-88)]; break;
      case 1: dst=PWk;  if(n<24) val=kkk_w1[(size_t)kk*24+n]; else if(n<48) val=mk_w1[(size_t)kk*24+(n-24)]; break;
      case 2: dst=PWv;  if(n<24) val=mv_w1[(size_t)kk*24+n]; break;
      case 3: dst=PWrg; if(n<120) val=gate_w1[(size_t)kk*120+n]; break;
      default: dst=PWmaa; if(n<112) val=maa_w1[(size_t)kk*112+n]; break;
    }
    dst[rem] = __float2bfloat16(val);
    return;
  }
  int i = idx - 491520;
  if (i < 294912){            // W2wa [2304][128]
    int n=i>>7, q=i&127, seg=n/768, c=n-seg*768;
    float val=0.f;
    if (seg==0){ if(q<64) val=dw2[(size_t)q*768+c]; }
    else if (seg==1){ if(q>=64&&q<88) val=aaa_w2[(size_t)(q-64)*768+c]; }
    else { if(q>=88&&q<112) val=ma_w2[(size_t)(q-88)*768+c]; }
    W2wa[i]=__float2bfloat16(val); return;
  }
  i -= 294912;
  if (i < 98304){             // W2k [1536][64]
    int n=i>>6, q=i&63, seg=n/768, c=n-seg*768;
    float val=0.f;
    if (seg==0){ if(q<24) val=kkk_w2[(size_t)q*768+c]; }
    else { if(q>=24&&q<48) val=mk_w2[(size_t)(q-24)*768+c]; }
    W2k[i]=__float2bfloat16(val); return;
  }
  i -= 98304;
  if (i < 24576){             // W2v [768][32]
    int c=i>>5, q=i&31;
    float val = (q<24) ? mv_w2[(size_t)q*768+c] : 0.f;
    W2v[i]=__float2bfloat16(val); return;
  }
  i -= 24576;
  if (i < 98304){             // W2g [768][128]
    int c=i>>7, q=i&127;
    float val = (q<120) ? gate_w2[(size_t)q*768+c] : 0.f;
    W2g[i]=__float2bfloat16(val);
  }
}

// ---------------- Wo GEMM: BM=64 x BN=128, 1D grid bn-major ----------------
__global__ __launch_bounds__(256) void gemm_wo(const bf16* __restrict__ A,
    const bf16* __restrict__ Bt, float* __restrict__ C, int N, int K) {
  const int bid = blockIdx.x;
  const int bm = (bid & 127)*64, bn = (bid >> 7)*128;
  __shared__ unsigned short As[64*32];
  __shared__ unsigned short Bs[128*32];
  const int tid = threadIdx.x, lane = tid&63, w = tid>>6;
  const int wr = w>>1, wc = w&1;
  const int lr = lane&15, kg = lane>>4;
  f32x4 zero = {0.f,0.f,0.f,0.f};
  f32x4 acc[2][4];
  #pragma unroll
  for (int m=0;m<2;m++)
    #pragma unroll
    for (int n=0;n<4;n++) acc[m][n]=zero;
  const size_t rowA = (size_t)(bm + w*16 + (lane>>2))*K + (lane&3)*8;
  const size_t rowB = (size_t)(bn + w*32 + (lane>>2))*K + (lane&3)*8;
  unsigned short* lA = As + w*16*32;
  unsigned short* lB = Bs + w*32*32;
  for (int k0=0; k0<K; k0+=32){
    GLDS16(A + rowA + k0,                 lA);
    GLDS16(Bt + rowB + k0,                lB);
    GLDS16(Bt + rowB + k0 + (size_t)16*K, lB + 512);
    __syncthreads();
    bf16x8 af[2], bfr[4];
    #pragma unroll
    for (int m=0;m<2;m++) af[m]  = *(const bf16x8*)(void*)(As + (wr*32+m*16+lr)*32 + kg*8);
    #pragma unroll
    for (int n=0;n<4;n++) bfr[n] = *(const bf16x8*)(void*)(Bs + (wc*64+n*16+lr)*32 + kg*8);
    #pragma unroll
    for (int m=0;m<2;m++)
      #pragma unroll
      for (int n=0;n<4;n++)
        acc[m][n] = __builtin_amdgcn_mfma_f32_16x16x32_bf16(af[m], bfr[n], acc[m][n], 0,0,0);
    __syncthreads();
  }
  #pragma unroll
  for (int m=0;m<2;m++)
    #pragma unroll
    for (int n=0;n<4;n++){
      size_t r0 = (size_t)(bm + wr*32 + m*16 + kg*4);
      int cc = bn + wc*64 + n*16 + lr;
      #pragma unroll
      for (int q=0;q<4;q++)
        C[(r0+q)*N + cc] = acc[m][n][q];
    }
}

// ---------------- gemm_tm: BM=64, N=112 mask, tanh ----------------
__global__ __launch_bounds__(256) void gemm_tm(const bf16* __restrict__ A,
    const bf16* __restrict__ Bt, float* __restrict__ C, int K) {
  const int bm = blockIdx.x*64;
  __shared__ unsigned short As[64*32];
  __shared__ unsigned short Bs[128*32];
  const int tid = threadIdx.x, lane = tid&63, w = tid>>6;
  const int wr = w>>1, wc = w&1;
  const int lr = lane&15, kg = lane>>4;
  f32x4 zero = {0.f,0.f,0.f,0.f};
  f32x4 acc[2][4];
  #pragma unroll
  for (int m=0;m<2;m++)
    #pragma unroll
    for (int n=0;n<4;n++) acc[m][n]=zero;
  const size_t rowA = (size_t)(bm + w*16 + (lane>>2))*K + (lane&3)*8;
  const size_t rowB = (size_t)(w*32 + (lane>>2))*K + (lane&3)*8;
  unsigned short* lA = As + w*16*32;
  unsigned short* lB = Bs + w*32*32;
  for (int k0=0; k0<K; k0+=32){
    GLDS16(A + rowA + k0,                 lA);
    GLDS16(Bt + rowB + k0,                lB);
    GLDS16(Bt + rowB + k0 + (size_t)16*K, lB + 512);
    __syncthreads();
    bf16x8 af[2], bfr[4];
    #pragma unroll
    for (int m=0;m<2;m++) af[m]  = *(const bf16x8*)(void*)(As + (wr*32+m*16+lr)*32 + kg*8);
    #pragma unroll
    for (int n=0;n<4;n++) bfr[n] = *(const bf16x8*)(void*)(Bs + (wc*64+n*16+lr)*32 + kg*8);
    #pragma unroll
    for (int m=0;m<2;m++)
      #pragma unroll
      for (int n=0;n<4;n++)
        acc[m][n] = __builtin_amdgcn_mfma_f32_16x16x32_bf16(af[m], bfr[n], acc[m][n], 0,0,0);
    __syncthreads();
  }
  #pragma unroll
  for (int m=0;m<2;m++)
    #pragma unroll
    for (int n=0;n<4;n++){
      size_t r0 = (size_t)(bm + wr*32 + m*16 + kg*4);
      int cc = wc*64 + n*16 + lr;
      if (cc < 112){
        #pragma unroll
        for (int q=0;q<4;q++)
          C[(r0+q)*112 + cc] = tanhf(acc[m][n][q]);
      }
    }
}

// ---------------- merged stage-1 + big r/k/v GEMMs; big path bn-major ----------------
struct S1P {
  const bf16* A[4];
  const bf16* Bt[4];
  bf16* C[4];
  int Ntrue[4];
  int Nalloc[4];
  int act[4];
};
struct G3 {
  const bf16* A[3];
  const bf16* Bt[3];
  bf16* C[3];
};
__global__ __launch_bounds__(256) void gemm_s1b3(S1P s, G3 g, int K) {
  const int bid = blockIdx.x;
  __shared__ unsigned short As[128*32];
  __shared__ unsigned short Bs[128*32];
  const int tid = threadIdx.x, lane = tid&63, w = tid>>6;
  const int wr = w>>1, wc = w&1;
  const int lr = lane&15, kg = lane>>4;
  int bm, bn, z;
  const bf16 *A, *Bt;
  const bool small = (bid < 256);
  if (small){
    z = bid>>6; bm = (bid&63)*128; bn = 0;
    A = s.A[z]; Bt = s.Bt[z];
  } else {
    int rem = bid-256;
    bn = (rem/192)*128; int t2 = rem%192;
    z = t2/64; bm = (t2%64)*128;
    A = g.A[z]; Bt = g.Bt[z];
  }
  f32x4 zero = {0.f,0.f,0.f,0.f};
  f32x4 acc[4][4];
  #pragma unroll
  for (int m=0;m<4;m++)
    #pragma unroll
    for (int n=0;n<4;n++) acc[m][n]=zero;
  const size_t rowA = (size_t)(bm + w*32 + (lane>>2))*K + (lane&3)*8;
  const size_t rowB = (size_t)(bn + w*32 + (lane>>2))*K + (lane&3)*8;
  unsigned short* lA = As + w*32*32;
  unsigned short* lB = Bs + w*32*32;
  for (int k0=0; k0<K; k0+=32){
    GLDS16(A + rowA + k0,                 lA);
    GLDS16(A + rowA + k0 + (size_t)16*K,  lA + 512);
    GLDS16(Bt + rowB + k0,                lB);
    GLDS16(Bt + rowB + k0 + (size_t)16*K, lB + 512);
    __syncthreads();
    bf16x8 af[4], bfr[4];
    #pragma unroll
    for (int m=0;m<4;m++) af[m]  = *(const bf16x8*)(void*)(As + (wr*64+m*16+lr)*32 + kg*8);
    #pragma unroll
    for (int n=0;n<4;n++) bfr[n] = *(const bf16x8*)(void*)(Bs + (wc*64+n*16+lr)*32 + kg*8);
    #pragma unroll
    for (int m=0;m<4;m++)
      #pragma unroll
      for (int n=0;n<4;n++)
        acc[m][n] = __builtin_amdgcn_mfma_f32_16x16x32_bf16(af[m], bfr[n], acc[m][n], 0,0,0);
    __syncthreads();
  }
  if (small){
    bf16* __restrict__ C = s.C[z];
    const int Ntrue = s.Ntrue[z], Nalloc = s.Nalloc[z], act = s.act[z];
    #pragma unroll
    for (int m=0;m<4;m++)
      #pragma unroll
      for (int n=0;n<4;n++){
        size_t r0 = (size_t)(bm + wr*64 + m*16 + kg*4);
        int cc = wc*64 + n*16 + lr;
        if (cc < Nalloc){
          #pragma unroll
          for (int q=0;q<4;q++){
            float val = acc[m][n][q];
            if      (act==1){ if (cc<64) val = tanhf(val); }
            else if (act==2){ if (cc<24) val = tanhf(val); }
            else if (act==3){ val = sigm(val); }
            if (cc >= Ntrue) val = 0.f;
            C[(r0+q)*Nalloc + cc] = __float2bfloat16(val);
          }
        }
      }
  } else {
    bf16* __restrict__ C = g.C[z];
    #pragma unroll
    for (int m=0;m<4;m++)
      #pragma unroll
      for (int n=0;n<4;n++){
        size_t r0 = (size_t)(bm + wr*64 + m*16 + kg*4);
        int cc = bn + wc*64 + n*16 + lr;
        #pragma unroll
        for (int q=0;q<4;q++)
          C[(r0+q)*Cdim + cc] = __float2bfloat16(acc[m][n][q]);
      }
  }
}

// ---------------- stage-2 batched GEMM, 1D exact grid, bn-major ----------------
struct Z4 {
  const bf16* A[4];
  const bf16* Bt[4];
  bf16* C[4];
  int N[4];
  int K[4];
};
__global__ __launch_bounds__(256) void gemm_z(Z4 p) {
  const int bid = blockIdx.x;          // 2688 = 42 bn-slots * 64 bm
  const int qs = bid >> 6;
  const int bm = (bid & 63) * 128;
  int z, bnq;
  if (qs < 18){ z=0; bnq=qs; }
  else if (qs < 30){ z=1; bnq=qs-18; }
  else if (qs < 36){ z=2; bnq=qs-30; }
  else { z=3; bnq=qs-36; }
  const int bn = bnq*128;
  const int N = p.N[z], K = p.K[z];
  const bf16* __restrict__ A  = p.A[z];
  const bf16* __restrict__ Bt = p.Bt[z];
  bf16* __restrict__ C = p.C[z];
  __shared__ unsigned short As[128*32];
  __shared__ unsigned short Bs[128*32];
  const int tid = threadIdx.x, lane = tid&63, w = tid>>6;
  const int wr = w>>1, wc = w&1;
  const int lr = lane&15, kg = lane>>4;
  f32x4 zero = {0.f,0.f,0.f,0.f};
  f32x4 acc[4][4];
  #pragma unroll
  for (int m=0;m<4;m++)
    #pragma unroll
    for (int n=0;n<4;n++) acc[m][n]=zero;
  const size_t rowA = (size_t)(bm + w*32 + (lane>>2))*K + (lane&3)*8;
  const size_t rowB = (size_t)(bn + w*32 + (lane>>2))*K + (lane&3)*8;
  unsigned short* lA = As + w*32*32;
  unsigned short* lB = Bs + w*32*32;
  for (int k0=0; k0<K; k0+=32){
    GLDS16(A + rowA + k0,                 lA);
    GLDS16(A + rowA + k0 + (size_t)16*K,  lA + 512);
    GLDS16(Bt + rowB + k0,                lB);
    GLDS16(Bt + rowB + k0 + (size_t)16*K, lB + 512);
    __syncthreads();
    bf16x8 af[4], bfr[4];
    #pragma unroll
    for (int m=0;m<4;m++) af[m]  = *(const bf16x8*)(void*)(As + (wr*64+m*16+lr)*32 + kg*8);
    #pragma unroll
    for (int n=0;n<4;n++) bfr[n] = *(const bf16x8*)(void*)(Bs + (wc*64+n*16+lr)*32 + kg*8);
    #pragma unroll
    for (int m=0;m<4;m++)
      #pragma unroll
      for (int n=0;n<4;n++)
        acc[m][n] = __builtin_amdgcn_mfma_f32_16x16x32_bf16(af[m], bfr[n], acc[m][n], 0,0,0);
    __syncthreads();
  }
  #pragma unroll
  for (int m=0;m<4;m++)
    #pragma unroll
    for (int n=0;n<4;n++){
      size_t r0 = (size_t)(bm + wr*64 + m*16 + kg*4);
      int cc = bn + wc*64 + n*16 + lr;
      #pragma unroll
      for (int q=0;q<4;q++)
        C[(r0+q)*N + cc] = __float2bfloat16(acc[m][n][q]);
    }
}

// ---------------- K2b: mix, 8 rows per block ----------------
__global__ __launch_bounds__(256) void k2_mix(const float* __restrict__ x,
    const float* __restrict__ tm, const float* __restrict__ w2,
    const float* __restrict__ mrg, const float* __restrict__ mwa,
    const float* __restrict__ mk_, const float* __restrict__ mv_,
    bf16* __restrict__ xrg, bf16* __restrict__ xwa, bf16* __restrict__ xk, bf16* __restrict__ xv) {
  const int row0 = blockIdx.x*8, tid = threadIdx.x;
  __shared__ float stm[8][112];
  for (int idx=tid; idx<8*112; idx+=256){
    int rr=idx/112, q=idx-rr*112;
    stm[rr][q]=tm[(size_t)(row0+rr)*112+q];
  }
  __syncthreads();
  for (int c=tid;c<Cdim;c+=256){
    float x8[8], d8[8];
    #pragma unroll
    for (int rr=0;rr<8;rr++){
      size_t i=(size_t)(row0+rr)*Cdim+c;
      float xv = x[i];
      float xp = (((row0+rr) & (Tdim-1)) == 0) ? 0.f : x[i - Cdim];
      x8[rr]=xv; d8[rr]=xp - xv;
    }
    float mrgc=mrg[c], mwac=mwa[c], mkc=mk_[c], mvc=mv_[c];
    float m0[8]={},m1[8]={},m2[8]={},m3[8]={};
    #pragma unroll 4
    for (int d=0; d<28; d++){
      float w0=w2[(size_t)(d)*Cdim + c];
      float w1=w2[(size_t)(28+d)*Cdim + c];
      float w2v=w2[(size_t)(56+d)*Cdim + c];
      float w3=w2[(size_t)(84+d)*Cdim + c];
      #pragma unroll
      for (int rr=0;rr<8;rr++){
        m0[rr]+=stm[rr][d]*w0; m1[rr]+=stm[rr][28+d]*w1;
        m2[rr]+=stm[rr][56+d]*w2v; m3[rr]+=stm[rr][84+d]*w3;
      }
    }
    #pragma unroll
    for (int rr=0;rr<8;rr++){
      size_t i=(size_t)(row0+rr)*Cdim+c;
      xrg[i]=__float2bfloat16(x8[rr] + d8[rr]*(mrgc+m0[rr]));
      xwa[i]=__float2bfloat16(x8[rr] + d8[rr]*(mwac+m1[rr]));
      xk[i] =__float2bfloat16(x8[rr] + d8[rr]*(mkc+m2[rr]));
      xv[i] =__float2bfloat16(x8[rr] + d8[rr]*(mvc+m3[rr]));
    }
  }
}

// ---------------- K5 v4: elementwise + in-wave head norm + rkab pack ----------------
__global__ __launch_bounds__(256) void k5_fuse(
    const bf16* __restrict__ zwa, const bf16* __restrict__ zk, const bf16* __restrict__ zv,
    const bf16* __restrict__ rbf, const bf16* __restrict__ kbf, bf16* __restrict__ vbf,
    const float* __restrict__ td, const float* __restrict__ aaaaa,
    const float* __restrict__ misc_a, const float* __restrict__ misc_k, const float* __restrict__ misc_v,
    const float* __restrict__ v1,
    float* __restrict__ wexp, unsigned short* __restrict__ rkab) {
  const int row = blockIdx.x, tid = threadIdx.x;
  #pragma unroll
  for (int it=0;it<3;it++){
    const int c = tid + it*256;
    const size_t i = (size_t)row*Cdim + c;
    float kraw = bf2f(kbf[i]);
    float v0   = bf2f(vbf[i]);
    float zd = bf2f(zwa[(size_t)row*2304 + c]);
    float za = bf2f(zwa[(size_t)row*2304 + 768 + c]);
    float zma= bf2f(zwa[(size_t)row*2304 + 1536 + c]);
    float zkk= bf2f(zk[(size_t)row*1536 + c]);
    float zmk= bf2f(zk[(size_t)row*1536 + 768 + c]);
    float zmv= bf2f(zv[i]);
    float w = -softplusf(-(td[c]+zd)) - 0.5f;
    wexp[i] = expf(-expf(w));
    float a  = sigm(aaaaa[c]+za);
    float ma = sigm(misc_a[c]+zma);
    float mk = sigm(misc_k[c]+zmk);
    float mv = sigm(misc_v[c]+zmv);
    vbf[i] = __float2bfloat16(v0 + (v1[i]-v0)*mv);
    float kf = kraw*(ma + a*(1.f-ma))*expf(fminf(w*mk,0.f));
    float kk = kraw + zkk;
    float ss = red32(kk*kk);
    float kkn = kk * (1.f/fmaxf(sqrtf(ss),1e-12f));
    unsigned rus = (unsigned)__builtin_bit_cast(unsigned short, rbf[i]);
    unsigned kus = (unsigned)__builtin_bit_cast(unsigned short, __float2bfloat16(kf));
    unsigned aus = (unsigned)__builtin_bit_cast(unsigned short, __float2bfloat16(-kkn));
    unsigned bus = (unsigned)__builtin_bit_cast(unsigned short, __float2bfloat16(kkn*a));
    uint2 pk;
    pk.x = rus | (kus<<16);
    pk.y = aus | (bus<<16);
    *(uint2*)&rkab[((size_t)row*Hdim + (c>>5))*128 + (size_t)(c&31)*4] = pk;
  }
}

// ---------------- K6 v11: sa-recursion (2-FMA serial chain) + depth-2 ping-pong ----------------
// sa_t = P_t + sa_{t-1}*BA_t + v_{t-1}*KA_t, where
//   P_t  = sum_j S_{t-2}[i][j] * w_{t-1}[j] * a_t[j]   (computed at iter t-1 from pre-update S)
//   BA_t = sum_j b_{t-1}[j]*a_t[j],  KA_t = sum_j k_{t-1}[j]*a_t[j]
// All reductions run off the serial chain (1 step of slack). Depth-2 TReg ping-pong
// (pA even / pB odd steps) guarantees a_{t+1} is loaded with a full iteration of slack,
// including across chunk boundaries (v8's proven vmcnt placement at t==14).
struct TRq { uint4 q; float2 w; unsigned short v; };
__global__ __launch_bounds__(64) void k6_wkv(const unsigned short* __restrict__ rkab,
    const float* __restrict__ wd, const unsigned short* __restrict__ vbf, bf16* __restrict__ y) {
  const int lane = threadIdx.x;
  const int bid = blockIdx.x;
  const int head = bid % (Bdim*Hdim);        // 8 blocks of a head stay on one XCD
  const int rq   = bid / (Bdim*Hdim);
  const int bb = head / Hdim, hh = head - bb*Hdim;
  const int i0 = rq*4 + (lane >> 4);         // global row 0..31
  const int jh = lane & 15;                  // j pair {2jh, 2jh+1}
  __shared__ __align__(16) unsigned short srk[2][16][128];
  __shared__ __align__(16) float sw[2][16][32];
  __shared__ __align__(16) unsigned short sv[2][16][32];
  const size_t wvbase = (size_t)bb*Tdim*Cdim + (size_t)hh*Ndim;
  float S0=0.f, S1=0.f;
  float saP=0.f, vlP=0.f;          // sa_{t-1}, v_{t-1}[i]
  float P=0.f, BA=0.f, KA=0.f;     // P_t, BA_t, KA_t for the upcoming step

  auto rkrow = [&](size_t t){ return (((size_t)bb*Tdim + t)*Hdim + hh)*128; };
  auto STAGE = [&](int c, int buf){
    const size_t tb = (size_t)c*16;
    #pragma unroll
    for (int i=0;i<4;i++)
      GLDS16(rkab + rkrow(tb + i*4 + (lane>>4)) + (size_t)(lane&15)*8, &srk[buf][i*4][0]);
    GLDS16(wd + wvbase + (tb +     (lane>>3))*Cdim + (lane&7)*4, &sw[buf][0][0]);
    GLDS16(wd + wvbase + (tb + 8 + (lane>>3))*Cdim + (lane&7)*4, &sw[buf][8][0]);
    GLDS16(vbf + wvbase + (tb + (lane>>2))*Cdim + (lane&3)*8, &sv[buf][0][0]);
  };
  auto LOADT = [&](TRq& d, int buf, int t){
    d.q = *(const uint4*)&srk[buf][t][jh*8];
    d.w = *(const float2*)&sw[buf][t][jh*2];
    d.v = sv[buf][t][i0];
  };

  STAGE(0, 0);
  asm volatile("s_waitcnt vmcnt(0)" ::: "memory");
  TRq pA, pB;
  LOADT(pA, 0, 0);
  LOADT(pB, 0, 1);
  int buf = 0;
  const int NCH = Tdim/16;
  for (int c=0; c<NCH; ++c){
    if (c+1 < NCH) STAGE(c+1, buf^1);
    const size_t yb = wvbase + (size_t)c*16*Cdim;
    #pragma unroll
    for (int t=0; t<16; t++){
      TRq& cur = (t&1) ? pB : pA;
      TRq& nxt = (t&1) ? pA : pB;            // holds step t+1 (stale only at final tail)
      const uint4 q = cur.q;
      const float2 cw = cur.w;
      const unsigned short cv = cur.v;
      // a_{t+1} from the other set (loaded one iteration ago -> full slack)
      const float na0 = __builtin_bit_cast(float, nxt.q.y<<16);
      const float na1 = __builtin_bit_cast(float, nxt.q.w<<16);
      // reload cur with step t+2 (depth-2; v8 boundary logic)
      const int tt = t+2;
      if (tt < 16) {
        LOADT(cur, buf, tt);
      } else if (c+1 < NCH) {
        if (tt == 16) asm volatile("s_waitcnt vmcnt(0)" ::: "memory");
        LOADT(cur, buf^1, tt-16);
      }
      const float r0 = __builtin_bit_cast(float, q.x<<16);
      const float k0 = __builtin_bit_cast(float, q.x & 0xFFFF0000u);
      const float b0 = __builtin_bit_cast(float, q.y & 0xFFFF0000u);
      const float r1 = __builtin_bit_cast(float, q.z<<16);
      const float k1 = __builtin_bit_cast(float, q.z & 0xFFFF0000u);
      const float b1 = __builtin_bit_cast(float, q.w & 0xFFFF0000u);
      const float vl = us2f(cv);
      // ---- serial chain: 2 chained FMAs ----
      const float sa = P + saP*BA + vlP*KA;
      // P_{t+1} partial from pre-update S (off-chain, 1 step slack)
      const float pa = S0*(cw.x*na0) + S1*(cw.y*na1);
      // state update
      S0 = S0*cw.x + (sa*b0 + vl*k0);
      S1 = S1*cw.y + (sa*b1 + vl*k1);
      // output (off-chain)
      float yv = S0*r0 + S1*r1;
      yv = red16(yv);
      if (jh == 0) y[yb + (size_t)t*Cdim + i0] = __float2bfloat16(yv);
      // reductions for step t+1 (off-chain)
      P  = red16(pa);
      BA = red16(b0*na0 + b1*na1);
      KA = red16(k0*na0 + k1*na1);
      saP = sa; vlP = vl;
    }
    buf ^= 1;
  }
}

// ---------------- K7 v5: GroupNorm + bonus + gate + v1 copy ----------------
__global__ __launch_bounds__(256) void k7_post(const bf16* __restrict__ y,
    const unsigned short* __restrict__ rkab, const bf16* __restrict__ v,
    const bf16* __restrict__ g, const float* __restrict__ faaaa,
    const float* __restrict__ lnw, const float* __restrict__ lnb,
    bf16* __restrict__ ygate,
    const float4* __restrict__ v1c, float4* __restrict__ outc) {
  const int row = blockIdx.x, tid = threadIdx.x;
  if (tid < 192) outc[(size_t)row*192 + tid] = v1c[(size_t)row*192 + tid];
  #pragma unroll
  for (int it=0; it<3; it++){
    const int c = tid + it*256;
    const size_t i = (size_t)row*Cdim + c;
    float yv = bf2f(y[i]);
    unsigned rk = *(const unsigned*)&rkab[((size_t)row*Hdim + (c>>5))*128 + (size_t)(c&31)*4];
    float rf = __builtin_bit_cast(float, rk<<16);
    float kf = __builtin_bit_cast(float, rk & 0xFFFF0000u);
    float bon = rf*kf*faaaa[c];
    float s  = red32(yv);
    float ss = red32(yv*yv);
    float bn = red32(bon);
    float mu = s*(1.f/Ndim);
    float var = ss*(1.f/Ndim) - mu*mu;
    float rs = rsqrtf(var + 6.4e-5f);
    float yn = (yv-mu)*rs*lnw[c]+lnb[c];
    ygate[i]=__float2bfloat16((yn + bn*bf2f(v[i]))*bf2f(g[i]));
  }
}

extern "C" void kernel_launch(void* const* d_in, const int* in_sizes, int n_in,
                              void* d_out, int out_size, void* d_ws, size_t ws_size,
                              hipStream_t stream) {
  const float* x      = (const float*)d_in[0];
  const float* v1     = (const float*)d_in[1];
  const float* maa_x  = (const float*)d_in[2];
  const float* maa_rg = (const float*)d_in[3];
  const float* maa_wa = (const float*)d_in[4];
  const float* maa_k  = (const float*)d_in[5];
  const float* maa_v  = (const float*)d_in[6];
  const float* time_decay = (const float*)d_in[7];
  const float* faaaa  = (const float*)d_in[8];
  const float* aaaaa  = (const float*)d_in[9];
  const float* maa_w1 = (const float*)d_in[10];
  const float* maa_w2 = (const float*)d_in[11];
  const float* dw1    = (const float*)d_in[12];
  const float* dw2    = (const float*)d_in[13];
  const float* aaa_w1 = (const float*)d_in[14];
  const float* aaa_w2 = (const float*)d_in[15];
  const float* kkk_w1 = (const float*)d_in[16];
  const float* kkk_w2 = (const float*)d_in[17];
  const float* gate_w1= (const float*)d_in[18];
  const float* gate_w2= (const float*)d_in[19];
  const float* ma_w1  = (const float*)d_in[20];
  const float* ma_w2  = (const float*)d_in[21];
  const float* misc_a = (const float*)d_in[22];
  const float* mk_w1  = (const float*)d_in[23];
  const float* mk_w2  = (const float*)d_in[24];
  const float* misc_k = (const float*)d_in[25];
  const float* mv_w1  = (const float*)d_in[26];
  const float* mv_w2  = (const float*)d_in[27];
  const float* misc_v = (const float*)d_in[28];
  const float* Wr     = (const float*)d_in[29];
  const float* Wk     = (const float*)d_in[30];
  const float* Wv     = (const float*)d_in[31];
  const float* Wo     = (const float*)d_in[32];
  const float* lnw    = (const float*)d_in[33];
  const float* lnb    = (const float*)d_in[34];
  float* out = (float*)d_out;

  float* ws = (float*)d_ws;
  const size_t BTC = (size_t)BTdim*Cdim;   // 6291456
  const size_t HB  = BTC/2;                // 3145728 f32 units
  float* wexp  = ws;                       // S1 @0 (2HB)
  bf16* kb_bf  = (bf16*)(ws + 2*HB);       // S2 @2 (1HB): kb_bf -> ybuf_bf
  bf16* ybuf_bf= (bf16*)(ws + 2*HB);
  bf16* vb_bf  = (bf16*)(ws + 3*HB);       // S3 @3 (1HB)
  bf16* xrg_bf = (bf16*)(ws + 4*HB);       // S4 @4 (3HB): xrg+xwa -> zwa
  bf16* xwa_bf = xrg_bf + BTC;
  bf16* zwa_bf = (bf16*)(ws + 4*HB);
  bf16* xk_bf  = (bf16*)(ws + 7*HB);       // S5 @7 (2HB): xk+xv -> zk
  bf16* xv_bf  = xk_bf + BTC;
  bf16* zk_bf  = (bf16*)(ws + 7*HB);
  bf16* xxx_bf = (bf16*)(ws + 9*HB);       // S6 @9 (1HB): xxx -> zv
  bf16* zv_bf  = (bf16*)(ws + 9*HB);
  float* tm    = ws + 10*HB;               // S7 @10 (1HB): tm -> zg
  bf16* zg_bf  = (bf16*)(ws + 10*HB);
  bf16* hwa_bf = (bf16*)(ws + 11*HB);      // S8 @11 (1HB)
  bf16* hk_bf  = hwa_bf + (size_t)BTdim*128;
  bf16* hv_bf  = hk_bf  + (size_t)BTdim*64;
  bf16* hrg_bf = hv_bf  + (size_t)BTdim*32;
  unsigned short* rkab = (unsigned short*)(ws + 12*HB);  // RK @12 (4HB)
  bf16* rb_bf  = (bf16*)(ws + 16*HB);      // @16 (1HB)
  bf16* yg_bf  = (bf16*)(ws + 17*HB);      // @17 (1HB)
  bf16* Wbase  = (bf16*)(ws + 18*HB);
  bf16* WtR = Wbase;
  bf16* WtK = WtR + 589824;
  bf16* WtV = WtK + 589824;
  bf16* WtO = WtV + 589824;
  bf16* PWwa = WtO + 589824;
  bf16* PWk  = PWwa + 98304;
  bf16* PWv  = PWk  + 98304;
  bf16* PWrg = PWv  + 98304;
  bf16* PWmaa= PWrg + 98304;
  bf16* W2wa = PWmaa + 98304;
  bf16* W2k  = W2wa + 294912;
  bf16* W2v  = W2k  + 98304;
  bf16* W2g  = W2v  + 24576;

  dim3 blk(256);
  k1_shift<<<dim3((BTdim*Cdim+255)/256), blk, 0, stream>>>(x, maa_x, xxx_bf);
  kcp<<<dim3(2304+3936), blk, 0, stream>>>(Wr,Wk,Wv,Wo, WtR,WtK,WtV,WtO,
                                           dw1,aaa_w1,ma_w1,kkk_w1,mk_w1,mv_w1,gate_w1,maa_w1,
                                           dw2,aaa_w2,ma_w2,kkk_w2,mk_w2,mv_w2,gate_w2,
                                           PWwa,PWk,PWv,PWrg,PWmaa, W2wa,W2k,W2v,W2g);
  gemm_tm<<<dim3(128), blk, 0, stream>>>(xxx_bf, PWmaa, tm, Cdim);
  k2_mix<<<dim3(BTdim/8), blk, 0, stream>>>(x, tm, maa_w2, maa_rg, maa_wa, maa_k, maa_v,
                                            xrg_bf, xwa_bf, xk_bf, xv_bf);
  {
    S1P s{};
    s.A[0]=xwa_bf; s.Bt[0]=PWwa; s.C[0]=hwa_bf; s.Ntrue[0]=112; s.Nalloc[0]=128; s.act[0]=1;
    s.A[1]=xk_bf;  s.Bt[1]=PWk;  s.C[1]=hk_bf;  s.Ntrue[1]=48;  s.Nalloc[1]=64;  s.act[1]=2;
    s.A[2]=xv_bf;  s.Bt[2]=PWv;  s.C[2]=hv_bf;  s.Ntrue[2]=24;  s.Nalloc[2]=32;  s.act[2]=0;
    s.A[3]=xrg_bf; s.Bt[3]=PWrg; s.C[3]=hrg_bf; s.Ntrue[3]=120; s.Nalloc[3]=128; s.act[3]=3;
    G3 g{};
    g.A[0]=xrg_bf; g.Bt[0]=WtR; g.C[0]=rb_bf;
    g.A[1]=xk_bf;  g.Bt[1]=WtK; g.C[1]=kb_bf;
    g.A[2]=xv_bf;  g.Bt[2]=WtV; g.C[2]=vb_bf;
    gemm_s1b3<<<dim3(256 + 3*384), blk, 0, stream>>>(s, g, Cdim);
  }
  {
    Z4 p{};
    p.A[0]=hwa_bf; p.Bt[0]=W2wa; p.C[0]=zwa_bf; p.N[0]=2304; p.K[0]=128;
    p.A[1]=hk_bf;  p.Bt[1]=W2k;  p.C[1]=zk_bf;  p.N[1]=1536; p.K[1]=64;
    p.A[2]=hv_bf;  p.Bt[2]=W2v;  p.C[2]=zv_bf;  p.N[2]=768;  p.K[2]=32;
    p.A[3]=hrg_bf; p.Bt[3]=W2g;  p.C[3]=zg_bf;  p.N[3]=768;  p.K[3]=128;
    gemm_z<<<dim3(42*64), blk, 0, stream>>>(p);
  }
  k5_fuse<<<dim3(BTdim), blk, 0, stream>>>(zwa_bf, zk_bf, zv_bf, rb_bf, kb_bf, vb_bf,
      time_decay, aaaaa, misc_a, misc_k, misc_v, v1, wexp, rkab);
  k6_wkv<<<dim3(Bdim*Hdim*8), dim3(64), 0, stream>>>(rkab, wexp,
      (const unsigned short*)vb_bf, ybuf_bf);
  k7_post<<<dim3(BTdim), blk, 0, stream>>>(ybuf_bf, rkab, vb_bf, zg_bf, faaaa, lnw, lnb, yg_bf,
                                           (const float4*)v1, (float4*)(out + BTC));
  gemm_wo<<<dim3(768), blk, 0, stream>>>(yg_bf, WtO, out, Cdim, Cdim);
}

// Round 15
// 492.496 us; speedup vs baseline: 1.1249x; 1.1249x over previous
//
#include <hip/hip_runtime.h>
#include <hip/hip_bf16.h>
#include <math.h>

#define Bdim 8
#define Tdim 1024
#define Cdim 768
#define Hdim 24
#define Ndim 32
#define BTdim (Bdim*Tdim)

typedef __attribute__((ext_vector_type(8))) short bf16x8;
typedef __attribute__((ext_vector_type(4))) float f32x4;
typedef __hip_bfloat16 bf16;

__device__ __forceinline__ float sigm(float x){ return 1.f/(1.f+expf(-x)); }
__device__ __forceinline__ float softplusf(float x){ return fmaxf(x,0.f) + log1pf(expf(-fabsf(x))); }
__device__ __forceinline__ float bf2f(bf16 v){ return __bfloat162float(v); }
__device__ __forceinline__ float us2f(unsigned short s){ return __builtin_bit_cast(float, (unsigned)s<<16); }

template<int CTRL>
__device__ __forceinline__ float dpp_add(float x){
  int xi = __builtin_bit_cast(int, x);
  int yi = __builtin_amdgcn_mov_dpp(xi, CTRL, 0xF, 0xF, true);
  return x + __builtin_bit_cast(float, yi);
}
__device__ __forceinline__ float red32(float x){
  x = dpp_add<0xB1>(x);
  x = dpp_add<0x4E>(x);
  x = dpp_add<0x141>(x);
  x = dpp_add<0x140>(x);
  x += __shfl_xor(x, 16);
  return x;
}
__device__ __forceinline__ float red16(float x){
  x = dpp_add<0xB1>(x);
  x = dpp_add<0x4E>(x);
  x = dpp_add<0x141>(x);
  x = dpp_add<0x140>(x);
  return x;
}

#define GLDS16(gp, lp) __builtin_amdgcn_global_load_lds((const __attribute__((address_space(1))) void*)(gp), (__attribute__((address_space(3))) void*)(lp), 16, 0, 0)

// ---------------- K1: token shift ----------------
__global__ void k1_shift(const float* __restrict__ x, const float* __restrict__ maa_x,
                         bf16* __restrict__ xxx) {
  int idx = blockIdx.x*256 + threadIdx.x;
  if (idx >= BTdim*Cdim) return;
  int c = idx % Cdim; int row = idx / Cdim; int t = row % Tdim;
  float xv = x[idx];
  float xp = (t==0) ? 0.f : x[idx - Cdim];
  xxx[idx] = __float2bfloat16(xv + (xp - xv)*maa_x[c]);
}

// ---------------- merged: big-weight transpose + small-weight pack ----------------
__global__ __launch_bounds__(256) void kcp(const float* __restrict__ W0, const float* __restrict__ W1,
    const float* __restrict__ W2, const float* __restrict__ W3,
    bf16* __restrict__ T0, bf16* __restrict__ T1, bf16* __restrict__ T2, bf16* __restrict__ T3,
    const float* __restrict__ dw1, const float* __restrict__ aaa_w1,
    const float* __restrict__ ma_w1, const float* __restrict__ kkk_w1, const float* __restrict__ mk_w1,
    const float* __restrict__ mv_w1, const float* __restrict__ gate_w1, const float* __restrict__ maa_w1,
    const float* __restrict__ dw2, const float* __restrict__ aaa_w2, const float* __restrict__ ma_w2,
    const float* __restrict__ kkk_w2, const float* __restrict__ mk_w2, const float* __restrict__ mv_w2,
    const float* __restrict__ gate_w2,
    bf16* __restrict__ PWwa, bf16* __restrict__ PWk, bf16* __restrict__ PWv,
    bf16* __restrict__ PWrg, bf16* __restrict__ PWmaa,
    bf16* __restrict__ W2wa, bf16* __restrict__ W2k, bf16* __restrict__ W2v, bf16* __restrict__ W2g){
  const int bid = blockIdx.x;
  if (bid < 2304) {
    __shared__ float tile[32][33];
    const int z = bid/576, rem = bid - z*576;
    const int by = (rem/24)*32, bx = (rem%24)*32;
    const float* Wsrc[4] = {W0,W1,W2,W3};
    bf16* Tdst[4] = {T0,T1,T2,T3};
    const float* W = Wsrc[z];
    bf16* T = Tdst[z];
    int tx = threadIdx.x & 31, ty = threadIdx.x >> 5;
    #pragma unroll
    for (int q=0;q<32;q+=8) tile[ty+q][tx] = W[(size_t)(by+ty+q)*Cdim + bx+tx];
    __syncthreads();
    #pragma unroll
    for (int q=0;q<32;q+=8) T[(size_t)(bx+ty+q)*Cdim + by+tx] = __float2bfloat16(tile[tx][ty+q]);
    return;
  }
  int idx = (bid-2304)*256 + threadIdx.x;
  if (idx < 491520) {
    int buf = idx / 98304, rem = idx - buf*98304;
    int n = rem / 768, kk = rem - n*768;
    float val = 0.f;
    bf16* dst;
    switch(buf){
      case 0: dst=PWwa; if(n<64) val=dw1[(size_t)kk*64+n]; else if(n<88) val=aaa_w1[(size_t)kk*24+(n-64)]; else if(n<112) val=ma_w1[(size_t)kk*24+(n-88)]; break;
      case 1: dst=PWk;  if(n<24) val=kkk_w1[(size_t)kk*24+n]; else if(n<48) val=mk_w1[(size_t)kk*24+(n-24)]; break;
      case 2: dst=PWv;  if(n<24) val=mv_w1[(size_t)kk*24+n]; break;
      case 3: dst=PWrg; if(n<120) val=gate_w1[(size_t)kk*120+n]; break;
      default: dst=PWmaa; if(n<112) val=maa_w1[(size_t)kk*112+n]; break;
    }
    dst[rem] = __float2bfloat16(val);
    return;
  }
  int i = idx - 491520;
  if (i < 294912){            // W2wa [2304][128]
    int n=i>>7, q=i&127, seg=n/768, c=n-seg*768;
    float val=0.f;
    if (seg==0){ if(q<64) val=dw2[(size_t)q*768+c]; }
    else if (seg==1){ if(q>=64&&q<88) val=aaa_w2[(size_t)(q-64)*768+c]; }
    else { if(q>=88&&q<112) val=ma_w2[(size_t)(q-88)*768+c]; }
    W2wa[i]=__float2bfloat16(val); return;
  }
  i -= 294912;
  if (i < 98304){             // W2k [1536][64]
    int n=i>>6, q=i&63, seg=n/768, c=n-seg*768;
    float val=0.f;
    if (seg==0){ if(q<24) val=kkk_w2[(size_t)q*768+c]; }
    else { if(q>=24&&q<48) val=mk_w2[(size_t)(q-24)*768+c]; }
    W2k[i]=__float2bfloat16(val); return;
  }
  i -= 98304;
  if (i < 24576){             // W2v [768][32]
    int c=i>>5, q=i&31;
    float val = (q<24) ? mv_w2[(size_t)q*768+c] : 0.f;
    W2v[i]=__float2bfloat16(val); return;
  }
  i -= 24576;
  if (i < 98304){             // W2g [768][128]
    int c=i>>7, q=i&127;
    float val = (q<120) ? gate_w2[(size_t)q*768+c] : 0.f;
    W2g[i]=__float2bfloat16(val);
  }
}

// ---------------- Wo GEMM: BM=64 x BN=128, 1D grid bn-major ----------------
__global__ __launch_bounds__(256) void gemm_wo(const bf16* __restrict__ A,
    const bf16* __restrict__ Bt, float* __restrict__ C, int N, int K) {
  const int bid = blockIdx.x;
  const int bm = (bid & 127)*64, bn = (bid >> 7)*128;
  __shared__ unsigned short As[64*32];
  __shared__ unsigned short Bs[128*32];
  const int tid = threadIdx.x, lane = tid&63, w = tid>>6;
  const int wr = w>>1, wc = w&1;
  const int lr = lane&15, kg = lane>>4;
  f32x4 zero = {0.f,0.f,0.f,0.f};
  f32x4 acc[2][4];
  #pragma unroll
  for (int m=0;m<2;m++)
    #pragma unroll
    for (int n=0;n<4;n++) acc[m][n]=zero;
  const size_t rowA = (size_t)(bm + w*16 + (lane>>2))*K + (lane&3)*8;
  const size_t rowB = (size_t)(bn + w*32 + (lane>>2))*K + (lane&3)*8;
  unsigned short* lA = As + w*16*32;
  unsigned short* lB = Bs + w*32*32;
  for (int k0=0; k0<K; k0+=32){
    GLDS16(A + rowA + k0,                 lA);
    GLDS16(Bt + rowB + k0,                lB);
    GLDS16(Bt + rowB + k0 + (size_t)16*K, lB + 512);
    __syncthreads();
    bf16x8 af[2], bfr[4];
    #pragma unroll
    for (int m=0;m<2;m++) af[m]  = *(const bf16x8*)(void*)(As + (wr*32+m*16+lr)*32 + kg*8);
    #pragma unroll
    for (int n=0;n<4;n++) bfr[n] = *(const bf16x8*)(void*)(Bs + (wc*64+n*16+lr)*32 + kg*8);
    #pragma unroll
    for (int m=0;m<2;m++)
      #pragma unroll
      for (int n=0;n<4;n++)
        acc[m][n] = __builtin_amdgcn_mfma_f32_16x16x32_bf16(af[m], bfr[n], acc[m][n], 0,0,0);
    __syncthreads();
  }
  #pragma unroll
  for (int m=0;m<2;m++)
    #pragma unroll
    for (int n=0;n<4;n++){
      size_t r0 = (size_t)(bm + wr*32 + m*16 + kg*4);
      int cc = bn + wc*64 + n*16 + lr;
      #pragma unroll
      for (int q=0;q<4;q++)
        C[(r0+q)*N + cc] = acc[m][n][q];
    }
}

// ---------------- gemm_tm: BM=64, N=112 mask, tanh ----------------
__global__ __launch_bounds__(256) void gemm_tm(const bf16* __restrict__ A,
    const bf16* __restrict__ Bt, float* __restrict__ C, int K) {
  const int bm = blockIdx.x*64;
  __shared__ unsigned short As[64*32];
  __shared__ unsigned short Bs[128*32];
  const int tid = threadIdx.x, lane = tid&63, w = tid>>6;
  const int wr = w>>1, wc = w&1;
  const int lr = lane&15, kg = lane>>4;
  f32x4 zero = {0.f,0.f,0.f,0.f};
  f32x4 acc[2][4];
  #pragma unroll
  for (int m=0;m<2;m++)
    #pragma unroll
    for (int n=0;n<4;n++) acc[m][n]=zero;
  const size_t rowA = (size_t)(bm + w*16 + (lane>>2))*K + (lane&3)*8;
  const size_t rowB = (size_t)(w*32 + (lane>>2))*K + (lane&3)*8;
  unsigned short* lA = As + w*16*32;
  unsigned short* lB = Bs + w*32*32;
  for (int k0=0; k0<K; k0+=32){
    GLDS16(A + rowA + k0,                 lA);
    GLDS16(Bt + rowB + k0,                lB);
    GLDS16(Bt + rowB + k0 + (size_t)16*K, lB + 512);
    __syncthreads();
    bf16x8 af[2], bfr[4];
    #pragma unroll
    for (int m=0;m<2;m++) af[m]  = *(const bf16x8*)(void*)(As + (wr*32+m*16+lr)*32 + kg*8);
    #pragma unroll
    for (int n=0;n<4;n++) bfr[n] = *(const bf16x8*)(void*)(Bs + (wc*64+n*16+lr)*32 + kg*8);
    #pragma unroll
    for (int m=0;m<2;m++)
      #pragma unroll
      for (int n=0;n<4;n++)
        acc[m][n] = __builtin_amdgcn_mfma_f32_16x16x32_bf16(af[m], bfr[n], acc[m][n], 0,0,0);
    __syncthreads();
  }
  #pragma unroll
  for (int m=0;m<2;m++)
    #pragma unroll
    for (int n=0;n<4;n++){
      size_t r0 = (size_t)(bm + wr*32 + m*16 + kg*4);
      int cc = wc*64 + n*16 + lr;
      if (cc < 112){
        #pragma unroll
        for (int q=0;q<4;q++)
          C[(r0+q)*112 + cc] = tanhf(acc[m][n][q]);
      }
    }
}

// ---------------- merged stage-1 + big r/k/v GEMMs; big path bn-major ----------------
struct S1P {
  const bf16* A[4];
  const bf16* Bt[4];
  bf16* C[4];
  int Ntrue[4];
  int Nalloc[4];
  int act[4];
};
struct G3 {
  const bf16* A[3];
  const bf16* Bt[3];
  bf16* C[3];
};
__global__ __launch_bounds__(256) void gemm_s1b3(S1P s, G3 g, int K) {
  const int bid = blockIdx.x;
  __shared__ unsigned short As[128*32];
  __shared__ unsigned short Bs[128*32];
  const int tid = threadIdx.x, lane = tid&63, w = tid>>6;
  const int wr = w>>1, wc = w&1;
  const int lr = lane&15, kg = lane>>4;
  int bm, bn, z;
  const bf16 *A, *Bt;
  const bool small = (bid < 256);
  if (small){
    z = bid>>6; bm = (bid&63)*128; bn = 0;
    A = s.A[z]; Bt = s.Bt[z];
  } else {
    int rem = bid-256;
    bn = (rem/192)*128; int t2 = rem%192;
    z = t2/64; bm = (t2%64)*128;
    A = g.A[z]; Bt = g.Bt[z];
  }
  f32x4 zero = {0.f,0.f,0.f,0.f};
  f32x4 acc[4][4];
  #pragma unroll
  for (int m=0;m<4;m++)
    #pragma unroll
    for (int n=0;n<4;n++) acc[m][n]=zero;
  const size_t rowA = (size_t)(bm + w*32 + (lane>>2))*K + (lane&3)*8;
  const size_t rowB = (size_t)(bn + w*32 + (lane>>2))*K + (lane&3)*8;
  unsigned short* lA = As + w*32*32;
  unsigned short* lB = Bs + w*32*32;
  for (int k0=0; k0<K; k0+=32){
    GLDS16(A + rowA + k0,                 lA);
    GLDS16(A + rowA + k0 + (size_t)16*K,  lA + 512);
    GLDS16(Bt + rowB + k0,                lB);
    GLDS16(Bt + rowB + k0 + (size_t)16*K, lB + 512);
    __syncthreads();
    bf16x8 af[4], bfr[4];
    #pragma unroll
    for (int m=0;m<4;m++) af[m]  = *(const bf16x8*)(void*)(As + (wr*64+m*16+lr)*32 + kg*8);
    #pragma unroll
    for (int n=0;n<4;n++) bfr[n] = *(const bf16x8*)(void*)(Bs + (wc*64+n*16+lr)*32 + kg*8);
    #pragma unroll
    for (int m=0;m<4;m++)
      #pragma unroll
      for (int n=0;n<4;n++)
        acc[m][n] = __builtin_amdgcn_mfma_f32_16x16x32_bf16(af[m], bfr[n], acc[m][n], 0,0,0);
    __syncthreads();
  }
  if (small){
    bf16* __restrict__ C = s.C[z];
    const int Ntrue = s.Ntrue[z], Nalloc = s.Nalloc[z], act = s.act[z];
    #pragma unroll
    for (int m=0;m<4;m++)
      #pragma unroll
      for (int n=0;n<4;n++){
        size_t r0 = (size_t)(bm + wr*64 + m*16 + kg*4);
        int cc = wc*64 + n*16 + lr;
        if (cc < Nalloc){
          #pragma unroll
          for (int q=0;q<4;q++){
            float val = acc[m][n][q];
            if      (act==1){ if (cc<64) val = tanhf(val); }
            else if (act==2){ if (cc<24) val = tanhf(val); }
            else if (act==3){ val = sigm(val); }
            if (cc >= Ntrue) val = 0.f;
            C[(r0+q)*Nalloc + cc] = __float2bfloat16(val);
          }
        }
      }
  } else {
    bf16* __restrict__ C = g.C[z];
    #pragma unroll
    for (int m=0;m<4;m++)
      #pragma unroll
      for (int n=0;n<4;n++){
        size_t r0 = (size_t)(bm + wr*64 + m*16 + kg*4);
        int cc = bn + wc*64 + n*16 + lr;
        #pragma unroll
        for (int q=0;q<4;q++)
          C[(r0+q)*Cdim + cc] = __float2bfloat16(acc[m][n][q]);
      }
  }
}

// ---------------- stage-2 batched GEMM, 1D exact grid, bn-major ----------------
struct Z4 {
  const bf16* A[4];
  const bf16* Bt[4];
  bf16* C[4];
  int N[4];
  int K[4];
};
__global__ __launch_bounds__(256) void gemm_z(Z4 p) {
  const int bid = blockIdx.x;          // 2688 = 42 bn-slots * 64 bm
  const int qs = bid >> 6;
  const int bm = (bid & 63) * 128;
  int z, bnq;
  if (qs < 18){ z=0; bnq=qs; }
  else if (qs < 30){ z=1; bnq=qs-18; }
  else if (qs < 36){ z=2; bnq=qs-30; }
  else { z=3; bnq=qs-36; }
  const int bn = bnq*128;
  const int N = p.N[z], K = p.K[z];
  const bf16* __restrict__ A  = p.A[z];
  const bf16* __restrict__ Bt = p.Bt[z];
  bf16* __restrict__ C = p.C[z];
  __shared__ unsigned short As[128*32];
  __shared__ unsigned short Bs[128*32];
  const int tid = threadIdx.x, lane = tid&63, w = tid>>6;
  const int wr = w>>1, wc = w&1;
  const int lr = lane&15, kg = lane>>4;
  f32x4 zero = {0.f,0.f,0.f,0.f};
  f32x4 acc[4][4];
  #pragma unroll
  for (int m=0;m<4;m++)
    #pragma unroll
    for (int n=0;n<4;n++) acc[m][n]=zero;
  const size_t rowA = (size_t)(bm + w*32 + (lane>>2))*K + (lane&3)*8;
  const size_t rowB = (size_t)(bn + w*32 + (lane>>2))*K + (lane&3)*8;
  unsigned short* lA = As + w*32*32;
  unsigned short* lB = Bs + w*32*32;
  for (int k0=0; k0<K; k0+=32){
    GLDS16(A + rowA + k0,                 lA);
    GLDS16(A + rowA + k0 + (size_t)16*K,  lA + 512);
    GLDS16(Bt + rowB + k0,                lB);
    GLDS16(Bt + rowB + k0 + (size_t)16*K, lB + 512);
    __syncthreads();
    bf16x8 af[4], bfr[4];
    #pragma unroll
    for (int m=0;m<4;m++) af[m]  = *(const bf16x8*)(void*)(As + (wr*64+m*16+lr)*32 + kg*8);
    #pragma unroll
    for (int n=0;n<4;n++) bfr[n] = *(const bf16x8*)(void*)(Bs + (wc*64+n*16+lr)*32 + kg*8);
    #pragma unroll
    for (int m=0;m<4;m++)
      #pragma unroll
      for (int n=0;n<4;n++)
        acc[m][n] = __builtin_amdgcn_mfma_f32_16x16x32_bf16(af[m], bfr[n], acc[m][n], 0,0,0);
    __syncthreads();
  }
  #pragma unroll
  for (int m=0;m<4;m++)
    #pragma unroll
    for (int n=0;n<4;n++){
      size_t r0 = (size_t)(bm + wr*64 + m*16 + kg*4);
      int cc = bn + wc*64 + n*16 + lr;
      #pragma unroll
      for (int q=0;q<4;q++)
        C[(r0+q)*N + cc] = __float2bfloat16(acc[m][n][q]);
    }
}

// ---------------- K2b: mix, 8 rows per block ----------------
__global__ __launch_bounds__(256) void k2_mix(const float* __restrict__ x,
    const float* __restrict__ tm, const float* __restrict__ w2,
    const float* __restrict__ mrg, const float* __restrict__ mwa,
    const float* __restrict__ mk_, const float* __restrict__ mv_,
    bf16* __restrict__ xrg, bf16* __restrict__ xwa, bf16* __restrict__ xk, bf16* __restrict__ xv) {
  const int row0 = blockIdx.x*8, tid = threadIdx.x;
  __shared__ float stm[8][112];
  for (int idx=tid; idx<8*112; idx+=256){
    int rr=idx/112, q=idx-rr*112;
    stm[rr][q]=tm[(size_t)(row0+rr)*112+q];
  }
  __syncthreads();
  for (int c=tid;c<Cdim;c+=256){
    float x8[8], d8[8];
    #pragma unroll
    for (int rr=0;rr<8;rr++){
      size_t i=(size_t)(row0+rr)*Cdim+c;
      float xv = x[i];
      float xp = (((row0+rr) & (Tdim-1)) == 0) ? 0.f : x[i - Cdim];
      x8[rr]=xv; d8[rr]=xp - xv;
    }
    float mrgc=mrg[c], mwac=mwa[c], mkc=mk_[c], mvc=mv_[c];
    float m0[8]={},m1[8]={},m2[8]={},m3[8]={};
    #pragma unroll 4
    for (int d=0; d<28; d++){
      float w0=w2[(size_t)(d)*Cdim + c];
      float w1=w2[(size_t)(28+d)*Cdim + c];
      float w2v=w2[(size_t)(56+d)*Cdim + c];
      float w3=w2[(size_t)(84+d)*Cdim + c];
      #pragma unroll
      for (int rr=0;rr<8;rr++){
        m0[rr]+=stm[rr][d]*w0; m1[rr]+=stm[rr][28+d]*w1;
        m2[rr]+=stm[rr][56+d]*w2v; m3[rr]+=stm[rr][84+d]*w3;
      }
    }
    #pragma unroll
    for (int rr=0;rr<8;rr++){
      size_t i=(size_t)(row0+rr)*Cdim+c;
      xrg[i]=__float2bfloat16(x8[rr] + d8[rr]*(mrgc+m0[rr]));
      xwa[i]=__float2bfloat16(x8[rr] + d8[rr]*(mwac+m1[rr]));
      xk[i] =__float2bfloat16(x8[rr] + d8[rr]*(mkc+m2[rr]));
      xv[i] =__float2bfloat16(x8[rr] + d8[rr]*(mvc+m3[rr]));
    }
  }
}

// ---------------- K5 v4: elementwise + in-wave head norm + rkab pack ----------------
__global__ __launch_bounds__(256) void k5_fuse(
    const bf16* __restrict__ zwa, const bf16* __restrict__ zk, const bf16* __restrict__ zv,
    const bf16* __restrict__ rbf, const bf16* __restrict__ kbf, bf16* __restrict__ vbf,
    const float* __restrict__ td, const float* __restrict__ aaaaa,
    const float* __restrict__ misc_a, const float* __restrict__ misc_k, const float* __restrict__ misc_v,
    const float* __restrict__ v1,
    float* __restrict__ wexp, unsigned short* __restrict__ rkab) {
  const int row = blockIdx.x, tid = threadIdx.x;
  #pragma unroll
  for (int it=0;it<3;it++){
    const int c = tid + it*256;
    const size_t i = (size_t)row*Cdim + c;
    float kraw = bf2f(kbf[i]);
    float v0   = bf2f(vbf[i]);
    float zd = bf2f(zwa[(size_t)row*2304 + c]);
    float za = bf2f(zwa[(size_t)row*2304 + 768 + c]);
    float zma= bf2f(zwa[(size_t)row*2304 + 1536 + c]);
    float zkk= bf2f(zk[(size_t)row*1536 + c]);
    float zmk= bf2f(zk[(size_t)row*1536 + 768 + c]);
    float zmv= bf2f(zv[i]);
    float w = -softplusf(-(td[c]+zd)) - 0.5f;
    wexp[i] = expf(-expf(w));
    float a  = sigm(aaaaa[c]+za);
    float ma = sigm(misc_a[c]+zma);
    float mk = sigm(misc_k[c]+zmk);
    float mv = sigm(misc_v[c]+zmv);
    vbf[i] = __float2bfloat16(v0 + (v1[i]-v0)*mv);
    float kf = kraw*(ma + a*(1.f-ma))*expf(fminf(w*mk,0.f));
    float kk = kraw + zkk;
    float ss = red32(kk*kk);
    float kkn = kk * (1.f/fmaxf(sqrtf(ss),1e-12f));
    unsigned rus = (unsigned)__builtin_bit_cast(unsigned short, rbf[i]);
    unsigned kus = (unsigned)__builtin_bit_cast(unsigned short, __float2bfloat16(kf));
    unsigned aus = (unsigned)__builtin_bit_cast(unsigned short, __float2bfloat16(-kkn));
    unsigned bus = (unsigned)__builtin_bit_cast(unsigned short, __float2bfloat16(kkn*a));
    uint2 pk;
    pk.x = rus | (kus<<16);
    pk.y = aus | (bus<<16);
    *(uint2*)&rkab[((size_t)row*Hdim + (c>>5))*128 + (size_t)(c&31)*4] = pk;
  }
}

// ---------------- K6 v10: 8 blocks/head, 4 rows x 16 lanes x 2 elems, packed rkab ----------------
__global__ __launch_bounds__(64) void k6_wkv(const unsigned short* __restrict__ rkab,
    const float* __restrict__ wd, const unsigned short* __restrict__ vbf, bf16* __restrict__ y) {
  const int lane = threadIdx.x;
  const int bid = blockIdx.x;
  const int head = bid % (Bdim*Hdim);
  const int rq   = bid / (Bdim*Hdim);
  const int bb = head / Hdim, hh = head - bb*Hdim;
  const int i0 = rq*4 + (lane >> 4);
  const int jh = lane & 15;
  __shared__ __align__(16) unsigned short srk[2][16][128];
  __shared__ __align__(16) float sw[2][16][32];
  __shared__ __align__(16) unsigned short sv[2][16][32];
  const size_t wvbase = (size_t)bb*Tdim*Cdim + (size_t)hh*Ndim;
  float S0=0.f, S1=0.f;

  auto rkrow = [&](size_t t){ return (((size_t)bb*Tdim + t)*Hdim + hh)*128; };
  auto STAGE = [&](int c, int buf){
    const size_t tb = (size_t)c*16;
    #pragma unroll
    for (int i=0;i<4;i++)
      GLDS16(rkab + rkrow(tb + i*4 + (lane>>4)) + (size_t)(lane&15)*8, &srk[buf][i*4][0]);
    GLDS16(wd + wvbase + (tb +     (lane>>3))*Cdim + (lane&7)*4, &sw[buf][0][0]);
    GLDS16(wd + wvbase + (tb + 8 + (lane>>3))*Cdim + (lane&7)*4, &sw[buf][8][0]);
    GLDS16(vbf + wvbase + (tb + (lane>>2))*Cdim + (lane&3)*8, &sv[buf][0][0]);
  };

  uint4 nq; float2 nw; unsigned short nv;
  auto LOADT = [&](int buf, int t){
    nq = *(const uint4*)&srk[buf][t][jh*8];
    nw = *(const float2*)&sw[buf][t][jh*2];
    nv = sv[buf][t][i0];
  };

  STAGE(0, 0);
  asm volatile("s_waitcnt vmcnt(0)" ::: "memory");
  LOADT(0, 0);
  int buf = 0;
  const int NCH = Tdim/16;
  for (int c=0; c<NCH; ++c){
    if (c+1 < NCH) STAGE(c+1, buf^1);
    const size_t yb = wvbase + (size_t)c*16*Cdim;
    #pragma unroll
    for (int t=0; t<16; t++){
      const uint4 q = nq;
      const float2 cw = nw;
      const unsigned short cv = nv;
      if (t < 15) {
        LOADT(buf, t+1);
      } else if (c+1 < NCH) {
        asm volatile("s_waitcnt vmcnt(0)" ::: "memory");
        LOADT(buf^1, 0);
      }
      float r0 = __builtin_bit_cast(float, q.x<<16);
      float k0 = __builtin_bit_cast(float, q.x & 0xFFFF0000u);
      float a0 = __builtin_bit_cast(float, q.y<<16);
      float b0 = __builtin_bit_cast(float, q.y & 0xFFFF0000u);
      float r1 = __builtin_bit_cast(float, q.z<<16);
      float k1 = __builtin_bit_cast(float, q.z & 0xFFFF0000u);
      float a1 = __builtin_bit_cast(float, q.w<<16);
      float b1 = __builtin_bit_cast(float, q.w & 0xFFFF0000u);
      const float vl = us2f(cv);
      float sa = S0*a0 + S1*a1;
      sa = red16(sa);
      S0 = S0*cw.x + (sa*b0 + vl*k0);
      S1 = S1*cw.y + (sa*b1 + vl*k1);
      float yv = S0*r0 + S1*r1;
      yv = red16(yv);
      if (jh == 0) y[yb + (size_t)t*Cdim + i0] = __float2bfloat16(yv);
    }
    buf ^= 1;
  }
}

// ---------------- K7 v5: GroupNorm + bonus + gate + v1 copy ----------------
__global__ __launch_bounds__(256) void k7_post(const bf16* __restrict__ y,
    const unsigned short* __restrict__ rkab, const bf16* __restrict__ v,
    const bf16* __restrict__ g, const float* __restrict__ faaaa,
    const float* __restrict__ lnw, const float* __restrict__ lnb,
    bf16* __restrict__ ygate,
    const float4* __restrict__ v1c, float4* __restrict__ outc) {
  const int row = blockIdx.x, tid = threadIdx.x;
  if (tid < 192) outc[(size_t)row*192 + tid] = v1c[(size_t)row*192 + tid];
  #pragma unroll
  for (int it=0; it<3; it++){
    const int c = tid + it*256;
    const size_t i = (size_t)row*Cdim + c;
    float yv = bf2f(y[i]);
    unsigned rk = *(const unsigned*)&rkab[((size_t)row*Hdim + (c>>5))*128 + (size_t)(c&31)*4];
    float rf = __builtin_bit_cast(float, rk<<16);
    float kf = __builtin_bit_cast(float, rk & 0xFFFF0000u);
    float bon = rf*kf*faaaa[c];
    float s  = red32(yv);
    float ss = red32(yv*yv);
    float bn = red32(bon);
    float mu = s*(1.f/Ndim);
    float var = ss*(1.f/Ndim) - mu*mu;
    float rs = rsqrtf(var + 6.4e-5f);
    float yn = (yv-mu)*rs*lnw[c]+lnb[c];
    ygate[i]=__float2bfloat16((yn + bn*bf2f(v[i]))*bf2f(g[i]));
  }
}

extern "C" void kernel_launch(void* const* d_in, const int* in_sizes, int n_in,
                              void* d_out, int out_size, void* d_ws, size_t ws_size,
                              hipStream_t stream) {
  const float* x      = (const float*)d_in[0];
  const float* v1     = (const float*)d_in[1];
  const float* maa_x  = (const float*)d_in[2];
  const float* maa_rg = (const float*)d_in[3];
  const float* maa_wa = (const float*)d_in[4];
  const float* maa_k  = (const float*)d_in[5];
  const float* maa_v  = (const float*)d_in[6];
  const float* time_decay = (const float*)d_in[7];
  const float* faaaa  = (const float*)d_in[8];
  const float* aaaaa  = (const float*)d_in[9];
  const float* maa_w1 = (const float*)d_in[10];
  const float* maa_w2 = (const float*)d_in[11];
  const float* dw1    = (const float*)d_in[12];
  const float* dw2    = (const float*)d_in[13];
  const float* aaa_w1 = (const float*)d_in[14];
  const float* aaa_w2 = (const float*)d_in[15];
  const float* kkk_w1 = (const float*)d_in[16];
  const float* kkk_w2 = (const float*)d_in[17];
  const float* gate_w1= (const float*)d_in[18];
  const float* gate_w2= (const float*)d_in[19];
  const float* ma_w1  = (const float*)d_in[20];
  const float* ma_w2  = (const float*)d_in[21];
  const float* misc_a = (const float*)d_in[22];
  const float* mk_w1  = (const float*)d_in[23];
  const float* mk_w2  = (const float*)d_in[24];
  const float* misc_k = (const float*)d_in[25];
  const float* mv_w1  = (const float*)d_in[26];
  const float* mv_w2  = (const float*)d_in[27];
  const float* misc_v = (const float*)d_in[28];
  const float* Wr     = (const float*)d_in[29];
  const float* Wk     = (const float*)d_in[30];
  const float* Wv     = (const float*)d_in[31];
  const float* Wo     = (const float*)d_in[32];
  const float* lnw    = (const float*)d_in[33];
  const float* lnb    = (const float*)d_in[34];
  float* out = (float*)d_out;

  float* ws = (float*)d_ws;
  const size_t BTC = (size_t)BTdim*Cdim;   // 6291456
  const size_t HB  = BTC/2;                // 3145728 f32 units
  float* wexp  = ws;                       // S1 @0 (2HB)
  bf16* kb_bf  = (bf16*)(ws + 2*HB);       // S2 @2 (1HB): kb_bf -> ybuf_bf
  bf16* ybuf_bf= (bf16*)(ws + 2*HB);
  bf16* vb_bf  = (bf16*)(ws + 3*HB);       // S3 @3 (1HB)
  bf16* xrg_bf = (bf16*)(ws + 4*HB);       // S4 @4 (3HB): xrg+xwa -> zwa
  bf16* xwa_bf = xrg_bf + BTC;
  bf16* zwa_bf = (bf16*)(ws + 4*HB);
  bf16* xk_bf  = (bf16*)(ws + 7*HB);       // S5 @7 (2HB): xk+xv -> zk
  bf16* xv_bf  = xk_bf + BTC;
  bf16* zk_bf  = (bf16*)(ws + 7*HB);
  bf16* xxx_bf = (bf16*)(ws + 9*HB);       // S6 @9 (1HB): xxx -> zv
  bf16* zv_bf  = (bf16*)(ws + 9*HB);
  float* tm    = ws + 10*HB;               // S7 @10 (1HB): tm -> zg
  bf16* zg_bf  = (bf16*)(ws + 10*HB);
  bf16* hwa_bf = (bf16*)(ws + 11*HB);      // S8 @11 (1HB)
  bf16* hk_bf  = hwa_bf + (size_t)BTdim*128;
  bf16* hv_bf  = hk_bf  + (size_t)BTdim*64;
  bf16* hrg_bf = hv_bf  + (size_t)BTdim*32;
  unsigned short* rkab = (unsigned short*)(ws + 12*HB);  // RK @12 (4HB)
  bf16* rb_bf  = (bf16*)(ws + 16*HB);      // @16 (1HB)
  bf16* yg_bf  = (bf16*)(ws + 17*HB);      // @17 (1HB)
  bf16* Wbase  = (bf16*)(ws + 18*HB);
  bf16* WtR = Wbase;
  bf16* WtK = WtR + 589824;
  bf16* WtV = WtK + 589824;
  bf16* WtO = WtV + 589824;
  bf16* PWwa = WtO + 589824;
  bf16* PWk  = PWwa + 98304;
  bf16* PWv  = PWk  + 98304;
  bf16* PWrg = PWv  + 98304;
  bf16* PWmaa= PWrg + 98304;
  bf16* W2wa = PWmaa + 98304;
  bf16* W2k  = W2wa + 294912;
  bf16* W2v  = W2k  + 98304;
  bf16* W2g  = W2v  + 24576;

  dim3 blk(256);
  k1_shift<<<dim3((BTdim*Cdim+255)/256), blk, 0, stream>>>(x, maa_x, xxx_bf);
  kcp<<<dim3(2304+3936), blk, 0, stream>>>(Wr,Wk,Wv,Wo, WtR,WtK,WtV,WtO,
                                           dw1,aaa_w1,ma_w1,kkk_w1,mk_w1,mv_w1,gate_w1,maa_w1,
                                           dw2,aaa_w2,ma_w2,kkk_w2,mk_w2,mv_w2,gate_w2,
                                           PWwa,PWk,PWv,PWrg,PWmaa, W2wa,W2k,W2v,W2g);
  gemm_tm<<<dim3(128), blk, 0, stream>>>(xxx_bf, PWmaa, tm, Cdim);
  k2_mix<<<dim3(BTdim/8), blk, 0, stream>>>(x, tm, maa_w2, maa_rg, maa_wa, maa_k, maa_v,
                                            xrg_bf, xwa_bf, xk_bf, xv_bf);
  {
    S1P s{};
    s.A[0]=xwa_bf; s.Bt[0]=PWwa; s.C[0]=hwa_bf; s.Ntrue[0]=112; s.Nalloc[0]=128; s.act[0]=1;
    s.A[1]=xk_bf;  s.Bt[1]=PWk;  s.C[1]=hk_bf;  s.Ntrue[1]=48;  s.Nalloc[1]=64;  s.act[1]=2;
    s.A[2]=xv_bf;  s.Bt[2]=PWv;  s.C[2]=hv_bf;  s.Ntrue[2]=24;  s.Nalloc[2]=32;  s.act[2]=0;
    s.A[3]=xrg_bf; s.Bt[3]=PWrg; s.C[3]=hrg_bf; s.Ntrue[3]=120; s.Nalloc[3]=128; s.act[3]=3;
    G3 g{};
    g.A[0]=xrg_bf; g.Bt[0]=WtR; g.C[0]=rb_bf;
    g.A[1]=xk_bf;  g.Bt[1]=WtK; g.C[1]=kb_bf;
    g.A[2]=xv_bf;  g.Bt[2]=WtV; g.C[2]=vb_bf;
    gemm_s1b3<<<dim3(256 + 3*384), blk, 0, stream>>>(s, g, Cdim);
  }
  {
    Z4 p{};
    p.A[0]=hwa_bf; p.Bt[0]=W2wa; p.C[0]=zwa_bf; p.N[0]=2304; p.K[0]=128;
    p.A[1]=hk_bf;  p.Bt[1]=W2k;  p.C[1]=zk_bf;  p.N[1]=1536; p.K[1]=64;
    p.A[2]=hv_bf;  p.Bt[2]=W2v;  p.C[2]=zv_bf;  p.N[2]=768;  p.K[2]=32;
    p.A[3]=hrg_bf; p.Bt[3]=W2g;  p.C[3]=zg_bf;  p.N[3]=768;  p.K[3]=128;
    gemm_z<<<dim3(42*64), blk, 0, stream>>>(p);
  }
  k5_fuse<<<dim3(BTdim), blk, 0, stream>>>(zwa_bf, zk_bf, zv_bf, rb_bf, kb_bf, vb_bf,
      time_decay, aaaaa, misc_a, misc_k, misc_v, v1, wexp, rkab);
  k6_wkv<<<dim3(Bdim*Hdim*8), dim3(64), 0, stream>>>(rkab, wexp,
      (const unsigned short*)vb_bf, ybuf_bf);
  k7_post<<<dim3(BTdim), blk, 0, stream>>>(ybuf_bf, rkab, vb_bf, zg_bf, faaaa, lnw, lnb, yg_bf,
                                           (const float4*)v1, (float4*)(out + BTC));
  gemm_wo<<<dim3(768), blk, 0, stream>>>(yg_bf, WtO, out, Cdim, Cdim);
}